// Round 6
// baseline (74.107 us; speedup 1.0000x reference)
//
#include <hip/hip_runtime.h>

// PackedAvgPool1d, kernel == stride == 2, H = 1024 (fixed by reference).
// Outputs (flat fp32, concatenated): y[new_total*H], new_seq_lens[B], new_cu[B+1].
//
// Persistent kernel, ONE OUTPUT ROW PER WAVE (R4 structure — best measured):
// each wave streams its row pair as 8 sequential 1KB loads from a single base
// (immediate-offset folding), combines, writes 4KB sequentially. Segment
// table (B <= 64) rebuilt in-register per block: coalesced seq_lens load +
// shfl_up scans; row->segment via ballot+popc. Nontemporal float4 (zero
// reuse). Grid sized so all blocks do an equal number of groups (no tail).

#define HDIM 1024
#define F4_PER_ROW 256   // HDIM/4
#define RPG 4            // rows per group = waves per block

typedef __attribute__((ext_vector_type(4))) float f4;

__global__ __launch_bounds__(256) void pool_fused_kernel(
    const f4* __restrict__ xv,
    const int* __restrict__ seq_lens,
    int B, int new_total,
    f4* __restrict__ yv,
    float* __restrict__ out_lens,
    float* __restrict__ out_cu)
{
    const int tid  = threadIdx.x;
    const int lane = tid & 63;
    const int wid  = tid >> 6;     // wave id 0..3

    // --- per-wave segment table (B <= 64) ---
    int L  = (lane < B) ? seq_lens[lane] : 0;
    int nl = (L + 1) >> 1;            // new_len = ceil(L/2)
    int S = nl, C = L;                // inclusive scans of nl and L
    #pragma unroll
    for (int d = 1; d < 64; d <<= 1) {
        int s2 = __shfl_up(S, d, 64);
        int c2 = __shfl_up(C, d, 64);
        if (lane >= d) { S += s2; C += c2; }
    }

    // block 0, wave 0 writes the fp32 meta tail
    if (blockIdx.x == 0 && tid < 64) {
        if (lane < B) {
            out_lens[lane]   = (float)nl;
            out_cu[lane + 1] = (float)S;
        }
        if (lane == 0) out_cu[0] = 0.0f;
    }

    const int ngroups = (new_total + RPG - 1) / RPG;

    for (int g = blockIdx.x; g < ngroups; g += gridDim.x) {
        const int r = g * RPG + wid;      // this wave's output row
        if (r >= new_total) continue;     // wave-uniform

        // segment b = #{i : S_i <= r}   (r is wave-uniform)
        const int b   = (int)__popcll(__ballot(S <= r));
        const int Sb  = __shfl(S,  b, 64);
        const int nlb = __shfl(nl, b, 64);
        const int Cb  = __shfl(C,  b, 64);
        const int Lb  = __shfl(L,  b, 64);
        const int j   = r - (Sb - nlb);        // row within segment
        const int i0  = (Cb - Lb) + 2 * j;     // input row index
        const bool pr = (2 * j + 1 < Lb);      // has second token (uniform)

        // sequential 8KB read off one base; offsets fold to immediates
        const f4* r0 = xv + (size_t)i0 * F4_PER_ROW + lane;
        f4 v0[4], v1[4];
        #pragma unroll
        for (int c = 0; c < 4; ++c)
            v0[c] = __builtin_nontemporal_load(r0 + c * 64);
        if (pr) {
            #pragma unroll
            for (int c = 0; c < 4; ++c)
                v1[c] = __builtin_nontemporal_load(r0 + F4_PER_ROW + c * 64);
            #pragma unroll
            for (int c = 0; c < 4; ++c)
                v0[c] = (v0[c] + v1[c]) * 0.5f;
        }

        // sequential 4KB write
        f4* o = yv + (size_t)r * F4_PER_ROW + lane;
        #pragma unroll
        for (int c = 0; c < 4; ++c)
            __builtin_nontemporal_store(v0[c], o + c * 64);
    }
}

extern "C" void kernel_launch(void* const* d_in, const int* in_sizes, int n_in,
                              void* d_out, int out_size, void* d_ws, size_t ws_size,
                              hipStream_t stream) {
    const f4*  xv       = (const f4*)d_in[0];
    const int* seq_lens = (const int*)d_in[1];
    // d_in[2] = cu_seq_lens (recomputed in-wave), d_in[3] = max_seq_len
    // (general path is exact for max_seq_len==1 too).

    const int B = in_sizes[1];                       // 64 (<= wave width)
    const int new_total = (out_size - (2 * B + 1)) / HDIM;

    float* y        = (float*)d_out;
    float* out_lens = y + (size_t)new_total * HDIM;
    float* out_cu   = out_lens + B;

    const int ngroups = (new_total + RPG - 1) / RPG;
    // balanced persistent grid: every block does exactly `iters` groups
    const int iters = (ngroups + 2047) / 2048;
    const int grid  = (ngroups + iters - 1) / iters;
    hipLaunchKernelGGL(pool_fused_kernel, dim3(grid), dim3(256), 0, stream,
                       xv, seq_lens, B, new_total, (f4*)y, out_lens, out_cu);
}

// Round 7
// 69.958 us; speedup vs baseline: 1.0593x; 1.0593x over previous
//
#include <hip/hip_runtime.h>

// PackedAvgPool1d, kernel == stride == 2, H = 1024 (fixed by reference).
// Outputs (flat fp32, concatenated): y[new_total*H], new_seq_lens[B], new_cu[B+1].
//
// Persistent kernel, ONE OUTPUT ROW PER WAVE (R4 structure — best measured):
// each wave streams its row pair as 8 sequential 1KB loads from a single base
// (immediate-offset folding), combines, writes 4KB sequentially. Segment
// table (B <= 64) rebuilt in-register per block: coalesced seq_lens load +
// shfl_up scans; row->segment via ballot+popc. Nontemporal float4 (zero
// reuse).
//
// Grid note (R6 lesson): grid must stay a multiple of 256 CUs for uniform
// blocks/CU. grid=2048 (8/CU) with grid-stride remainder is naturally
// balanced; a "block-balanced" 1929-block grid put 8 blocks on some CUs and
// 7 on others -> ~6% regression.

#define HDIM 1024
#define F4_PER_ROW 256   // HDIM/4
#define RPG 4            // rows per group = waves per block

typedef __attribute__((ext_vector_type(4))) float f4;

__global__ __launch_bounds__(256) void pool_fused_kernel(
    const f4* __restrict__ xv,
    const int* __restrict__ seq_lens,
    int B, int new_total,
    f4* __restrict__ yv,
    float* __restrict__ out_lens,
    float* __restrict__ out_cu)
{
    const int tid  = threadIdx.x;
    const int lane = tid & 63;
    const int wid  = tid >> 6;     // wave id 0..3

    // --- per-wave segment table (B <= 64) ---
    int L  = (lane < B) ? seq_lens[lane] : 0;
    int nl = (L + 1) >> 1;            // new_len = ceil(L/2)
    int S = nl, C = L;                // inclusive scans of nl and L
    #pragma unroll
    for (int d = 1; d < 64; d <<= 1) {
        int s2 = __shfl_up(S, d, 64);
        int c2 = __shfl_up(C, d, 64);
        if (lane >= d) { S += s2; C += c2; }
    }

    // block 0, wave 0 writes the fp32 meta tail
    if (blockIdx.x == 0 && tid < 64) {
        if (lane < B) {
            out_lens[lane]   = (float)nl;
            out_cu[lane + 1] = (float)S;
        }
        if (lane == 0) out_cu[0] = 0.0f;
    }

    const int ngroups = (new_total + RPG - 1) / RPG;

    for (int g = blockIdx.x; g < ngroups; g += gridDim.x) {
        const int r = g * RPG + wid;      // this wave's output row
        if (r >= new_total) continue;     // wave-uniform

        // segment b = #{i : S_i <= r}   (r is wave-uniform)
        const int b   = (int)__popcll(__ballot(S <= r));
        const int Sb  = __shfl(S,  b, 64);
        const int nlb = __shfl(nl, b, 64);
        const int Cb  = __shfl(C,  b, 64);
        const int Lb  = __shfl(L,  b, 64);
        const int j   = r - (Sb - nlb);        // row within segment
        const int i0  = (Cb - Lb) + 2 * j;     // input row index
        const bool pr = (2 * j + 1 < Lb);      // has second token (uniform)

        // sequential 8KB read off one base; offsets fold to immediates
        const f4* r0 = xv + (size_t)i0 * F4_PER_ROW + lane;
        f4 v0[4], v1[4];
        #pragma unroll
        for (int c = 0; c < 4; ++c)
            v0[c] = __builtin_nontemporal_load(r0 + c * 64);
        if (pr) {
            #pragma unroll
            for (int c = 0; c < 4; ++c)
                v1[c] = __builtin_nontemporal_load(r0 + F4_PER_ROW + c * 64);
            #pragma unroll
            for (int c = 0; c < 4; ++c)
                v0[c] = (v0[c] + v1[c]) * 0.5f;
        }

        // sequential 4KB write
        f4* o = yv + (size_t)r * F4_PER_ROW + lane;
        #pragma unroll
        for (int c = 0; c < 4; ++c)
            __builtin_nontemporal_store(v0[c], o + c * 64);
    }
}

extern "C" void kernel_launch(void* const* d_in, const int* in_sizes, int n_in,
                              void* d_out, int out_size, void* d_ws, size_t ws_size,
                              hipStream_t stream) {
    const f4*  xv       = (const f4*)d_in[0];
    const int* seq_lens = (const int*)d_in[1];
    // d_in[2] = cu_seq_lens (recomputed in-wave), d_in[3] = max_seq_len
    // (general path is exact for max_seq_len==1 too).

    const int B = in_sizes[1];                       // 64 (<= wave width)
    const int new_total = (out_size - (2 * B + 1)) / HDIM;

    float* y        = (float*)d_out;
    float* out_lens = y + (size_t)new_total * HDIM;
    float* out_cu   = out_lens + B;

    const int ngroups = (new_total + RPG - 1) / RPG;
    const int grid = ngroups < 2048 ? ngroups : 2048;
    hipLaunchKernelGGL(pool_fused_kernel, dim3(grid), dim3(256), 0, stream,
                       xv, seq_lens, B, new_total, (f4*)y, out_lens, out_cu);
}